// Round 4
// baseline (319.506 us; speedup 1.0000x reference)
//
#include <hip/hip_runtime.h>

// B=256 samples, D=2048 dims, N=16384 bank rows. Dominant cost:
// sims = normalize(inputs) @ features^T / 0.05 -> per-row logsumexp.
// GEMM is HBM-bound on features (134 MB f32, read once ~= 21 us floor).
// Design: NO LDS, NO BARRIERS. Each wave streams its own MFMA fragments
// from global with a 3-deep register pipeline; B coalesces 128B/row since
// the mfma B-frag k-layout ((lane>>4)*8) maps 4 lanes onto contiguous f32.

constexpr int Bn = 256;     // batch
constexpr int Dk = 2048;    // feature dim
constexpr int Nn = 16384;   // bank rows
constexpr int NPB = 512;    // partial chunks (Nn/64 blocks * 2 wn)
constexpr float TEMP_INV = 20.0f;

typedef float f32x4 __attribute__((ext_vector_type(4)));
typedef short s16x8 __attribute__((ext_vector_type(8)));

__device__ inline unsigned short f2bf(float f) {
  union { float f; unsigned u; } v; v.f = f;
  unsigned r = v.u + 0x7FFFu + ((v.u >> 16) & 1u);   // RNE
  return (unsigned short)(r >> 16);
}

// ---------------- kernel 1: normalize inputs -> bf16 + exact s_own ----------
__global__ __launch_bounds__(256) void norm_sown_kernel(
    const float* __restrict__ x, const float* __restrict__ feats,
    const int* __restrict__ targets, unsigned short* __restrict__ xb,
    float* __restrict__ s_own) {
  int row = blockIdx.x, t = threadIdx.x;
  const float* xr = x + (size_t)row * Dk;
  const float* fr = feats + (size_t)targets[row] * Dk;
  float4 a  = *(const float4*)(xr + t * 8);
  float4 b  = *(const float4*)(xr + t * 8 + 4);
  float4 fa = *(const float4*)(fr + t * 8);
  float4 fb = *(const float4*)(fr + t * 8 + 4);
  float ss = a.x*a.x + a.y*a.y + a.z*a.z + a.w*a.w
           + b.x*b.x + b.y*b.y + b.z*b.z + b.w*b.w;
  float dt = a.x*fa.x + a.y*fa.y + a.z*fa.z + a.w*fa.w
           + b.x*fb.x + b.y*fb.y + b.z*fb.z + b.w*fb.w;
  #pragma unroll
  for (int d = 1; d < 64; d <<= 1) {
    ss += __shfl_xor(ss, d, 64);
    dt += __shfl_xor(dt, d, 64);
  }
  __shared__ float rs[4], rd[4];
  if ((t & 63) == 0) { rs[t >> 6] = ss; rd[t >> 6] = dt; }
  __syncthreads();
  float inv = rsqrtf(rs[0] + rs[1] + rs[2] + rs[3]);
  union { unsigned short s[8]; uint4 v; } pk;
  pk.s[0] = f2bf(a.x*inv); pk.s[1] = f2bf(a.y*inv);
  pk.s[2] = f2bf(a.z*inv); pk.s[3] = f2bf(a.w*inv);
  pk.s[4] = f2bf(b.x*inv); pk.s[5] = f2bf(b.y*inv);
  pk.s[6] = f2bf(b.z*inv); pk.s[7] = f2bf(b.w*inv);
  *(uint4*)(xb + (size_t)row * Dk + t * 8) = pk.v;
  if (t == 0) s_own[row] = (rd[0] + rd[1] + rd[2] + rd[3]) * inv * TEMP_INV;
}

// ---------------- kernel 2: barrier-free streaming GEMM + partial LSE -------
// grid = 256 blocks (one N-panel of 64 cols each), 512 threads = 8 waves.
// wave (wm in [0,4), wn in [0,2)): 64 rows x 32 cols, K pipelined 3-deep.
__global__ __launch_bounds__(512) void gemm_kernel(
    const unsigned short* __restrict__ xb, const float* __restrict__ feats,
    float* __restrict__ pmax, float* __restrict__ psum) {
  int tid = threadIdx.x;
  int w = tid >> 6, lane = tid & 63;
  int wm = w >> 1, wn = w & 1;
  int nb = blockIdx.x;
  int n0 = nb * 64 + wn * 32;
  int lr = lane & 15;        // row/col within a 16-tile
  int lk = (lane >> 4) * 8;  // k offset within a k32 step

  // fragment base pointers (static-indexed everywhere)
  const unsigned short* aptr[4];
  #pragma unroll
  for (int mt = 0; mt < 4; ++mt)
    aptr[mt] = xb + (size_t)(wm * 64 + mt * 16 + lr) * Dk + lk;
  const float* bptr[2];
  #pragma unroll
  for (int nt = 0; nt < 2; ++nt)
    bptr[nt] = feats + (size_t)(n0 + nt * 16 + lr) * Dk + lk;

  f32x4 acc[4][2];
  #pragma unroll
  for (int mt = 0; mt < 4; ++mt)
    #pragma unroll
    for (int nt = 0; nt < 2; ++nt)
      acc[mt][nt] = (f32x4){0.f, 0.f, 0.f, 0.f};

  s16x8 Af[4][4];      // [buf][mt] bf16 A fragments
  float4 Bf[4][2][2];  // [buf][nt][half] f32 B fragments (cvt at use)

  // 8 load instrs per k32 step (4 A x 16B, 2x2 B x 16B)
#define LOADS(B_, K32) do {                                              \
    int _k = (K32) * 32;                                                 \
    _Pragma("unroll") for (int mt = 0; mt < 4; ++mt)                     \
      Af[B_][mt] = *(const s16x8*)(aptr[mt] + _k);                       \
    _Pragma("unroll") for (int nt = 0; nt < 2; ++nt) {                   \
      Bf[B_][nt][0] = *(const float4*)(bptr[nt] + _k);                   \
      Bf[B_][nt][1] = *(const float4*)(bptr[nt] + _k + 4);               \
    }                                                                    \
  } while (0)

#define COMPUTE(B_) do {                                                 \
    s16x8 bb[2];                                                         \
    _Pragma("unroll") for (int nt = 0; nt < 2; ++nt) {                   \
      union { unsigned short s[8]; s16x8 v; } pk;                        \
      pk.s[0] = f2bf(Bf[B_][nt][0].x); pk.s[1] = f2bf(Bf[B_][nt][0].y);  \
      pk.s[2] = f2bf(Bf[B_][nt][0].z); pk.s[3] = f2bf(Bf[B_][nt][0].w);  \
      pk.s[4] = f2bf(Bf[B_][nt][1].x); pk.s[5] = f2bf(Bf[B_][nt][1].y);  \
      pk.s[6] = f2bf(Bf[B_][nt][1].z); pk.s[7] = f2bf(Bf[B_][nt][1].w);  \
      bb[nt] = pk.v;                                                     \
    }                                                                    \
    _Pragma("unroll") for (int mt = 0; mt < 4; ++mt)                     \
      _Pragma("unroll") for (int nt = 0; nt < 2; ++nt)                   \
        acc[mt][nt] = __builtin_amdgcn_mfma_f32_16x16x32_bf16(           \
            Af[B_][mt], bb[nt], acc[mt][nt], 0, 0, 0);                   \
  } while (0)

  // prologue: fill all 4 buffers (k32 steps 0..3)
  LOADS(0, 0); LOADS(1, 1); LOADS(2, 2); LOADS(3, 3);
  // main loop: 64 k32-steps, 4 per iteration; prefetch distance 4 (3 deep
  // at each compute). Tail prefetches clamp to step 63 (loaded, unused).
  for (int kt = 0; kt < 64; kt += 4) {
    int k4 = (kt + 4 < 64) ? kt + 4 : 63;
    int k5 = (kt + 5 < 64) ? kt + 5 : 63;
    int k6 = (kt + 6 < 64) ? kt + 6 : 63;
    int k7 = (kt + 7 < 64) ? kt + 7 : 63;
    COMPUTE(0); LOADS(0, k4);
    COMPUTE(1); LOADS(1, k5);
    COMPUTE(2); LOADS(2, k6);
    COMPUTE(3); LOADS(3, k7);
  }
#undef LOADS
#undef COMPUTE

  // epilogue: per-row partial max / sumexp over this wave's 32 cols.
  // C/D layout: col = lane&15, row = (lane>>4)*4 + reg
  int pb = nb * 2 + wn;
  #pragma unroll
  for (int mt = 0; mt < 4; ++mt) {
    #pragma unroll
    for (int rg = 0; rg < 4; ++rg) {
      float v0 = acc[mt][0][rg] * TEMP_INV;
      float v1 = acc[mt][1][rg] * TEMP_INV;
      float m = fmaxf(v0, v1);
      #pragma unroll
      for (int d = 1; d < 16; d <<= 1) m = fmaxf(m, __shfl_xor(m, d, 64));
      float s = __expf(v0 - m) + __expf(v1 - m);
      #pragma unroll
      for (int d = 1; d < 16; d <<= 1) s += __shfl_xor(s, d, 64);
      if ((lane & 15) == 0) {
        int row = wm * 64 + mt * 16 + (lane >> 4) * 4 + rg;
        pmax[(size_t)row * NPB + pb] = m;
        psum[(size_t)row * NPB + pb] = s;
      }
    }
  }
}

// ---------------- kernel 3: parallel LSE combine (one block per row) --------
__global__ __launch_bounds__(512) void combine_kernel(
    const float* __restrict__ pmax, const float* __restrict__ psum,
    float* __restrict__ lse) {
  int row = blockIdx.x, t = threadIdx.x;
  float m = pmax[(size_t)row * NPB + t];
  float s = psum[(size_t)row * NPB + t];
  float mw = m;
  #pragma unroll
  for (int d = 1; d < 64; d <<= 1) mw = fmaxf(mw, __shfl_xor(mw, d, 64));
  __shared__ float redm[8], reds[8];
  if ((t & 63) == 0) redm[t >> 6] = mw;
  __syncthreads();
  float M = fmaxf(fmaxf(fmaxf(redm[0], redm[1]), fmaxf(redm[2], redm[3])),
                  fmaxf(fmaxf(redm[4], redm[5]), fmaxf(redm[6], redm[7])));
  float sv = s * __expf(m - M);
  #pragma unroll
  for (int d = 1; d < 64; d <<= 1) sv += __shfl_xor(sv, d, 64);
  if ((t & 63) == 0) reds[t >> 6] = sv;
  __syncthreads();
  if (t == 0) {
    float S = reds[0] + reds[1] + reds[2] + reds[3]
            + reds[4] + reds[5] + reds[6] + reds[7];
    lse[row] = M + logf(S);
  }
}

// ---------------- kernel 4: group logic -> loss -----------------------------
__global__ __launch_bounds__(256) void finish_kernel(
    const float* __restrict__ lse, const float* __restrict__ s_own,
    const int* __restrict__ targets, const int* __restrict__ cams,
    float* __restrict__ out) {
  int i = threadIdx.x;
  float mylse = lse[i];

  __shared__ float so[256]; __shared__ int tg[256], cmn[256];
  __shared__ float gfirst[256];
  so[i] = s_own[i]; tg[i] = targets[i]; cmn[i] = cams[i];
  __syncthreads();
  int ti = tg[i], ci = cmn[i]; float soi = so[i];
  float gmin = 1e30f;
  bool grp_first = true, psid_first = true;
  for (int j = 0; j < 256; ++j) {
    if (tg[j] == ti) {
      if (j < i) psid_first = false;
      if (cmn[j] == ci) {
        gmin = fminf(gmin, so[j]);
        if (j < i) grp_first = false;
      }
    }
  }
  bool ismin = (soi <= gmin);
  gfirst[i] = grp_first ? 1.f : 0.f;
  __syncthreads();
  float ngroups = 0.f; bool prior = false;
  for (int j = 0; j < 256; ++j) {
    if (tg[j] == ti) {
      ngroups += gfirst[j];
      if (j < i && cmn[j] == ci && so[j] <= gmin) prior = true;
    }
  }
  float contrib = (ismin && !prior) ? (mylse - soi) / ngroups : 0.f;
  float pf = psid_first ? 1.f : 0.f;
  #pragma unroll
  for (int d = 1; d < 64; d <<= 1) {
    contrib += __shfl_xor(contrib, d, 64);
    pf += __shfl_xor(pf, d, 64);
  }
  __shared__ float rc[4], rp[4];
  if ((i & 63) == 0) { rc[i >> 6] = contrib; rp[i >> 6] = pf; }
  __syncthreads();
  if (i == 0) out[0] = (rc[0] + rc[1] + rc[2] + rc[3]) / (rp[0] + rp[1] + rp[2] + rp[3]);
}

extern "C" void kernel_launch(void* const* d_in, const int* in_sizes, int n_in,
                              void* d_out, int out_size, void* d_ws, size_t ws_size,
                              hipStream_t stream) {
  const float* inputs  = (const float*)d_in[0];
  const float* feats   = (const float*)d_in[1];
  const int*   targets = (const int*)d_in[2];
  const int*   cams    = (const int*)d_in[3];
  float* out = (float*)d_out;
  char* ws = (char*)d_ws;
  // ws: s_own 1KB | lse 1KB | pad | pmax 512KB | psum 512KB | x_bf16 1MB
  float* s_own    = (float*)(ws + 1024);
  float* lse      = (float*)(ws + 2048);
  float* pmax     = (float*)(ws + 4096);
  float* psum     = (float*)(ws + 4096 + 512 * 1024);
  unsigned short* xb = (unsigned short*)(ws + 4096 + 1024 * 1024);

  norm_sown_kernel<<<Bn, 256, 0, stream>>>(inputs, feats, targets, xb, s_own);
  gemm_kernel<<<Nn / 64, 512, 0, stream>>>(xb, feats, pmax, psum);
  combine_kernel<<<Bn, NPB, 0, stream>>>(pmax, psum, lse);
  finish_kernel<<<1, 256, 0, stream>>>(lse, s_own, targets, cams, out);
}